// Round 1
// baseline (2478.040 us; speedup 1.0000x reference)
//
#include <hip/hip_runtime.h>
#include <cstdint>
#include <cstddef>

// LinearCrypto: B=64, F=512, L=512, P=96, H=8, hd=64, M=B*512=32768
// Pipeline:
//  revin_stats -> revin_apply(transpose to (B,L,F)) -> [row_stats_ln ->
//  QKV gemms(LN fused) -> kv_reduce -> attn_out(in-place over Q) ->
//  Wo gemm(+residual, optional transposed write)] x2 -> feat_linear -> final_out
//
// ws layout (floats): b0,b1,b2,b3 (4 x 16.78M), kv (2.10M), z/meanb/stdb/lmu/linv
// (5 x 32768), ybuf (3.15M)  => ~277 MiB

#define EPS_ATTN 1e-6f
#define EPS_LN   1e-5f
#define EPS_REVIN 1e-5f

// ---------- RevIN stats: mean/std(ddof=1)+eps per (b,f) row of x (B,F,L) ----------
__global__ __launch_bounds__(256) void revin_stats_k(const float* __restrict__ x,
                                                     float* __restrict__ meanb,
                                                     float* __restrict__ stdb) {
  int wid = threadIdx.x >> 6, lane = threadIdx.x & 63;
  int row = blockIdx.x * 4 + wid;               // b*F + f
  const float* xr = x + (size_t)row * 512;
  float s1 = 0.f, s2 = 0.f;
#pragma unroll
  for (int i = 0; i < 8; ++i) {
    float v = xr[lane + i * 64];
    s1 += v; s2 += v * v;
  }
#pragma unroll
  for (int off = 32; off; off >>= 1) { s1 += __shfl_down(s1, off); s2 += __shfl_down(s2, off); }
  if (lane == 0) {
    float m = s1 * (1.f / 512.f);
    float var = fmaxf((s2 - 512.f * m * m) * (1.f / 511.f), 0.f);
    meanb[row] = m;
    stdb[row]  = sqrtf(var) + EPS_REVIN;
  }
}

// ---------- RevIN apply + transpose: hA[b,l,f] = (x[b,f,l]-mean)/std*rg[f]+rb[f] ----------
__global__ __launch_bounds__(256) void revin_apply_k(const float* __restrict__ x,
                                                     const float* __restrict__ meanb,
                                                     const float* __restrict__ stdb,
                                                     const float* __restrict__ rg,
                                                     const float* __restrict__ rb,
                                                     float* __restrict__ hA) {
  __shared__ float tile[32][33];
  int b = blockIdx.z;
  int f0 = blockIdx.y * 32, l0 = blockIdx.x * 32;
  int tx = threadIdx.x, ty = threadIdx.y;       // 32 x 8
  const float* xb = x + (size_t)b * 512 * 512;
#pragma unroll
  for (int k = 0; k < 32; k += 8) {
    int f = f0 + ty + k;
    float m = meanb[b * 512 + f], s = stdb[b * 512 + f];
    float v = xb[(size_t)f * 512 + l0 + tx];
    tile[ty + k][tx] = (v - m) / s * rg[f] + rb[f];
  }
  __syncthreads();
  float* hb = hA + (size_t)b * 512 * 512;
#pragma unroll
  for (int k = 0; k < 32; k += 8) {
    int l = l0 + ty + k;
    hb[(size_t)l * 512 + f0 + tx] = tile[tx][ty + k];
  }
}

// ---------- LayerNorm row stats: mu, inv = 1/sqrt(var_biased+eps) per row of 512 ----------
__global__ __launch_bounds__(256) void row_stats_ln_k(const float* __restrict__ in,
                                                      float* __restrict__ mu,
                                                      float* __restrict__ inv) {
  int wid = threadIdx.x >> 6, lane = threadIdx.x & 63;
  int row = blockIdx.x * 4 + wid;
  const float* r = in + (size_t)row * 512;
  float s1 = 0.f, s2 = 0.f;
#pragma unroll
  for (int i = 0; i < 8; ++i) {
    float v = r[lane + i * 64];
    s1 += v; s2 += v * v;
  }
#pragma unroll
  for (int off = 32; off; off >>= 1) { s1 += __shfl_down(s1, off); s2 += __shfl_down(s2, off); }
  if (lane == 0) {
    float m = s1 * (1.f / 512.f);
    float var = fmaxf(s2 * (1.f / 512.f) - m * m, 0.f);
    mu[row]  = m;
    inv[row] = 1.f / sqrtf(var + EPS_LN);
  }
}

// ---------- GEMM: out[m,n] = act( A'(m,:)·W(n,:) + bias[n] ) [+resid] ----------
// A' = LN-transformed A if LNF. ACT: 0 none, 1 elu+1. OUTMODE: 0 plain,
// 1 +resid (same layout), 2 +resid then transposed write to (B,F,L).
template <int ACT, int OUTMODE, int LNF>
__global__ __launch_bounds__(256) void gemm512k(const float* __restrict__ A,
                                                const float* __restrict__ W,
                                                const float* __restrict__ bias,
                                                const float* __restrict__ resid,
                                                const float* __restrict__ mu,
                                                const float* __restrict__ inv,
                                                const float* __restrict__ lng,
                                                const float* __restrict__ lnb,
                                                float* __restrict__ out) {
  __shared__ float As[16][68];
  __shared__ float Ws[16][68];
  const int m0 = blockIdx.x * 64;
  const int n0 = blockIdx.y * 64;
  const int tid = threadIdx.x;
  const int tx = tid & 15, ty = tid >> 4;
  const int lr = tid >> 2;              // 0..63 row within tile
  const int lc = (tid & 3) << 2;        // 0,4,8,12 k-offset
  const float* Ap = A + (size_t)(m0 + lr) * 512 + lc;
  const float* Wp = W + (size_t)(n0 + lr) * 512 + lc;
  float mu_r = 0.f, inv_r = 0.f;
  if constexpr (LNF) { mu_r = mu[m0 + lr]; inv_r = inv[m0 + lr]; }
  float acc[4][4] = {};
  for (int k0 = 0; k0 < 512; k0 += 16) {
    float4 av = *(const float4*)(Ap + k0);
    float4 wv = *(const float4*)(Wp + k0);
    if constexpr (LNF) {
      float4 gv = *(const float4*)(lng + k0 + lc);
      float4 bv = *(const float4*)(lnb + k0 + lc);
      av.x = (av.x - mu_r) * inv_r * gv.x + bv.x;
      av.y = (av.y - mu_r) * inv_r * gv.y + bv.y;
      av.z = (av.z - mu_r) * inv_r * gv.z + bv.z;
      av.w = (av.w - mu_r) * inv_r * gv.w + bv.w;
    }
    As[lc + 0][lr] = av.x; As[lc + 1][lr] = av.y; As[lc + 2][lr] = av.z; As[lc + 3][lr] = av.w;
    Ws[lc + 0][lr] = wv.x; Ws[lc + 1][lr] = wv.y; Ws[lc + 2][lr] = wv.z; Ws[lc + 3][lr] = wv.w;
    __syncthreads();
#pragma unroll
    for (int k = 0; k < 16; ++k) {
      float4 a = *(const float4*)&As[k][ty * 4];
      float4 bb = *(const float4*)&Ws[k][tx * 4];
      acc[0][0] = fmaf(a.x, bb.x, acc[0][0]); acc[0][1] = fmaf(a.x, bb.y, acc[0][1]);
      acc[0][2] = fmaf(a.x, bb.z, acc[0][2]); acc[0][3] = fmaf(a.x, bb.w, acc[0][3]);
      acc[1][0] = fmaf(a.y, bb.x, acc[1][0]); acc[1][1] = fmaf(a.y, bb.y, acc[1][1]);
      acc[1][2] = fmaf(a.y, bb.z, acc[1][2]); acc[1][3] = fmaf(a.y, bb.w, acc[1][3]);
      acc[2][0] = fmaf(a.z, bb.x, acc[2][0]); acc[2][1] = fmaf(a.z, bb.y, acc[2][1]);
      acc[2][2] = fmaf(a.z, bb.z, acc[2][2]); acc[2][3] = fmaf(a.z, bb.w, acc[2][3]);
      acc[3][0] = fmaf(a.w, bb.x, acc[3][0]); acc[3][1] = fmaf(a.w, bb.y, acc[3][1]);
      acc[3][2] = fmaf(a.w, bb.z, acc[3][2]); acc[3][3] = fmaf(a.w, bb.w, acc[3][3]);
    }
    __syncthreads();
  }
  float bi[4];
#pragma unroll
  for (int j = 0; j < 4; ++j) bi[j] = bias[n0 + tx * 4 + j];

  if constexpr (OUTMODE == 2) {
    __shared__ float Cs[64][65];
#pragma unroll
    for (int i = 0; i < 4; ++i) {
      int m = m0 + ty * 4 + i;
      const float* rp = resid + (size_t)m * 512 + n0 + tx * 4;
#pragma unroll
      for (int j = 0; j < 4; ++j) Cs[ty * 4 + i][tx * 4 + j] = acc[i][j] + bi[j] + rp[j];
    }
    __syncthreads();
    int b = m0 >> 9, l0 = m0 & 511;
    int fl = tid >> 2, q = tid & 3;
    float* op = out + ((size_t)(b * 512) + n0 + fl) * 512 + l0 + q * 16;
#pragma unroll
    for (int s = 0; s < 16; s += 4) {
      float4 v;
      v.x = Cs[q * 16 + s + 0][fl];
      v.y = Cs[q * 16 + s + 1][fl];
      v.z = Cs[q * 16 + s + 2][fl];
      v.w = Cs[q * 16 + s + 3][fl];
      *(float4*)(op + s) = v;
    }
  } else {
#pragma unroll
    for (int i = 0; i < 4; ++i) {
      size_t m = m0 + ty * 4 + i;
      float* op = out + m * 512 + n0 + tx * 4;
      float4 v;
      float c0 = acc[i][0] + bi[0], c1 = acc[i][1] + bi[1];
      float c2 = acc[i][2] + bi[2], c3 = acc[i][3] + bi[3];
      if constexpr (ACT == 1) {
        c0 = (c0 > 0.f) ? c0 + 1.f : __expf(c0);
        c1 = (c1 > 0.f) ? c1 + 1.f : __expf(c1);
        c2 = (c2 > 0.f) ? c2 + 1.f : __expf(c2);
        c3 = (c3 > 0.f) ? c3 + 1.f : __expf(c3);
      }
      if constexpr (OUTMODE == 1) {
        const float* rp = resid + m * 512 + n0 + tx * 4;
        c0 += rp[0]; c1 += rp[1]; c2 += rp[2]; c3 += rp[3];
      }
      v.x = c0; v.y = c1; v.z = c2; v.w = c3;
      *(float4*)op = v;
    }
  }
}

// ---------- KV[b,h,d,e] = sum_n K[b,n,hd+d]*V[b,n,hd+e];  Z[b,h,d] = sum_n K ----------
__global__ __launch_bounds__(256) void kv_reduce_k(const float* __restrict__ Kb,
                                                   const float* __restrict__ Vb,
                                                   float* __restrict__ KV,
                                                   float* __restrict__ Z) {
  int bh = blockIdx.x;
  int b = bh >> 3, h = bh & 7;
  __shared__ float Ks[16][65];
  __shared__ float Vs[16][65];
  int tid = threadIdx.x;
  int tx = tid & 15, ty = tid >> 4;
  int lr = tid >> 4;                 // n-local 0..15
  int lc = (tid & 15) * 4;           // d-col 0..60
  const float* Kp = Kb + (size_t)b * 512 * 512 + h * 64 + lc;
  const float* Vp = Vb + (size_t)b * 512 * 512 + h * 64 + lc;
  float acc[4][4] = {};
  float zac[4] = {};
  for (int n0 = 0; n0 < 512; n0 += 16) {
    float4 kv4 = *(const float4*)(Kp + (size_t)(n0 + lr) * 512);
    float4 vv4 = *(const float4*)(Vp + (size_t)(n0 + lr) * 512);
    Ks[lr][lc + 0] = kv4.x; Ks[lr][lc + 1] = kv4.y; Ks[lr][lc + 2] = kv4.z; Ks[lr][lc + 3] = kv4.w;
    Vs[lr][lc + 0] = vv4.x; Vs[lr][lc + 1] = vv4.y; Vs[lr][lc + 2] = vv4.z; Vs[lr][lc + 3] = vv4.w;
    __syncthreads();
#pragma unroll
    for (int n = 0; n < 16; ++n) {
      float kk[4], vv[4];
#pragma unroll
      for (int i = 0; i < 4; ++i) kk[i] = Ks[n][ty * 4 + i];
#pragma unroll
      for (int j = 0; j < 4; ++j) vv[j] = Vs[n][tx * 4 + j];
#pragma unroll
      for (int i = 0; i < 4; ++i) {
        zac[i] += kk[i];
#pragma unroll
        for (int j = 0; j < 4; ++j) acc[i][j] = fmaf(kk[i], vv[j], acc[i][j]);
      }
    }
    __syncthreads();
  }
  float* kvp = KV + (size_t)bh * 4096;
#pragma unroll
  for (int i = 0; i < 4; ++i)
#pragma unroll
    for (int j = 0; j < 4; ++j) kvp[(ty * 4 + i) * 64 + tx * 4 + j] = acc[i][j];
  if (tx == 0) {
#pragma unroll
    for (int i = 0; i < 4; ++i) Z[bh * 64 + ty * 4 + i] = zac[i];
  }
}

// ---------- O = (Q @ KV) / (Q·Z + eps), written in-place over Q ----------
__global__ __launch_bounds__(256) void attn_out_k(float* __restrict__ Qb,
                                                  const float* __restrict__ KV,
                                                  const float* __restrict__ Z) {
  int bh = blockIdx.y;
  int b = bh >> 3, h = bh & 7;
  int n0 = blockIdx.x * 16;
  __shared__ float KVs[64][65];
  __shared__ float Qs[16][65];
  __shared__ float Zs[64];
  int tid = threadIdx.x;
  {
    int d = tid >> 2, c = (tid & 3) * 16;
    const float* kvp = KV + (size_t)bh * 4096 + d * 64 + c;
#pragma unroll
    for (int s = 0; s < 16; s += 4) {
      float4 v = *(const float4*)(kvp + s);
      KVs[d][c + s] = v.x; KVs[d][c + s + 1] = v.y; KVs[d][c + s + 2] = v.z; KVs[d][c + s + 3] = v.w;
    }
  }
  if (tid < 64) Zs[tid] = Z[bh * 64 + tid];
  float* qbase = Qb + (size_t)(b * 512 + n0) * 512 + h * 64;
  {
    int n = tid >> 4, c = (tid & 15) * 4;
    float4 v = *(const float4*)(qbase + (size_t)n * 512 + c);
    Qs[n][c] = v.x; Qs[n][c + 1] = v.y; Qs[n][c + 2] = v.z; Qs[n][c + 3] = v.w;
  }
  __syncthreads();
  int nl = tid >> 4, te = tid & 15;
  float a0 = 0.f, a1 = 0.f, a2 = 0.f, a3 = 0.f;
  float nrm = EPS_ATTN;
#pragma unroll
  for (int d = 0; d < 64; ++d) {
    float q = Qs[nl][d];
    nrm = fmaf(q, Zs[d], nrm);
    a0 = fmaf(q, KVs[d][te * 4 + 0], a0);
    a1 = fmaf(q, KVs[d][te * 4 + 1], a1);
    a2 = fmaf(q, KVs[d][te * 4 + 2], a2);
    a3 = fmaf(q, KVs[d][te * 4 + 3], a3);
  }
  float iv = 1.f / nrm;
  float4 v; v.x = a0 * iv; v.y = a1 * iv; v.z = a2 * iv; v.w = a3 * iv;
  *(float4*)(qbase + (size_t)nl * 512 + te * 4) = v;
}

// ---------- y[b,f,p] = sum_l h2[b,f,l]*Wlin[f,p,l] + blin[f,p] (one block per f) ----------
__global__ __launch_bounds__(256) void feat_linear_k(const float* __restrict__ h2,
                                                     const float* __restrict__ Wlin,
                                                     const float* __restrict__ blin,
                                                     float* __restrict__ Y) {
  int f = blockIdx.x;
  __shared__ float Hs[64][65];
  __shared__ float Ws2[96][65];
  int tid = threadIdx.x;
  int tx = tid & 15, ty = tid >> 4;    // tx: 6 p's each, ty: 4 b's each
  float acc[4][6] = {};
  for (int l0 = 0; l0 < 512; l0 += 64) {
    {
      int bb = tid >> 2, c = (tid & 3) * 16;
      const float* hp = h2 + ((size_t)bb * 512 + f) * 512 + l0 + c;
#pragma unroll
      for (int s = 0; s < 16; s += 4) {
        float4 v = *(const float4*)(hp + s);
        Hs[bb][c + s] = v.x; Hs[bb][c + s + 1] = v.y; Hs[bb][c + s + 2] = v.z; Hs[bb][c + s + 3] = v.w;
      }
    }
#pragma unroll
    for (int s = 0; s < 6; ++s) {
      int q = s * 256 + tid;           // 1536 float4 total
      int p = q >> 4, c = (q & 15) * 4;
      float4 v = *(const float4*)(Wlin + ((size_t)f * 96 + p) * 512 + l0 + c);
      Ws2[p][c] = v.x; Ws2[p][c + 1] = v.y; Ws2[p][c + 2] = v.z; Ws2[p][c + 3] = v.w;
    }
    __syncthreads();
#pragma unroll 8
    for (int l = 0; l < 64; ++l) {
      float hv[4], wv[6];
#pragma unroll
      for (int i = 0; i < 4; ++i) hv[i] = Hs[ty * 4 + i][l];
#pragma unroll
      for (int j = 0; j < 6; ++j) wv[j] = Ws2[tx * 6 + j][l];
#pragma unroll
      for (int i = 0; i < 4; ++i)
#pragma unroll
        for (int j = 0; j < 6; ++j) acc[i][j] = fmaf(hv[i], wv[j], acc[i][j]);
    }
    __syncthreads();
  }
#pragma unroll
  for (int i = 0; i < 4; ++i) {
    int b = ty * 4 + i;
#pragma unroll
    for (int j = 0; j < 6; ++j) {
      int p = tx * 6 + j;
      Y[((size_t)b * 512 + f) * 96 + p] = acc[i][j] + blin[f * 96 + p];
    }
  }
}

// ---------- out[b,p] = bproj + sum_f Wproj[f]*((Y-rb)/rg*std + mean) ----------
__global__ __launch_bounds__(256) void final_out_k(const float* __restrict__ Y,
                                                   const float* __restrict__ meanb,
                                                   const float* __restrict__ stdb,
                                                   const float* __restrict__ rg,
                                                   const float* __restrict__ rb,
                                                   const float* __restrict__ Wproj,
                                                   const float* __restrict__ bproj,
                                                   float* __restrict__ out) {
  int b = blockIdx.x;
  __shared__ float cs[512];
  __shared__ float kred[4];
  int t = threadIdx.x;
  float kpart = 0.f;
  for (int f = t; f < 512; f += 256) {
    float sd = stdb[b * 512 + f], mn = meanb[b * 512 + f];
    float g = rg[f], rbv = rb[f], wp = Wproj[f];
    float c = wp * sd / g;
    cs[f] = c;
    kpart += wp * mn - c * rbv;
  }
#pragma unroll
  for (int off = 32; off; off >>= 1) kpart += __shfl_down(kpart, off);
  int wid = t >> 6, lane = t & 63;
  if (lane == 0) kred[wid] = kpart;
  __syncthreads();
  float K = kred[0] + kred[1] + kred[2] + kred[3] + bproj[0];
  if (t < 96) {
    float acc = 0.f;
    for (int f = 0; f < 512; ++f) acc = fmaf(cs[f], Y[((size_t)b * 512 + f) * 96 + t], acc);
    out[b * 96 + t] = acc + K;
  }
}

extern "C" void kernel_launch(void* const* d_in, const int* in_sizes, int n_in,
                              void* d_out, int out_size, void* d_ws, size_t ws_size,
                              hipStream_t stream) {
  const float* x    = (const float*)d_in[0];
  const float* rg   = (const float*)d_in[1];
  const float* rb   = (const float*)d_in[2];
  const float* n1g  = (const float*)d_in[3];
  const float* n1b  = (const float*)d_in[4];
  const float* n2g  = (const float*)d_in[5];
  const float* n2b  = (const float*)d_in[6];
  const float* tWq  = (const float*)d_in[7];
  const float* tbq  = (const float*)d_in[8];
  const float* tWk  = (const float*)d_in[9];
  const float* tbk  = (const float*)d_in[10];
  const float* tWv  = (const float*)d_in[11];
  const float* tbv  = (const float*)d_in[12];
  const float* tWo  = (const float*)d_in[13];
  const float* tbo  = (const float*)d_in[14];
  const float* fWq  = (const float*)d_in[15];
  const float* fbq  = (const float*)d_in[16];
  const float* fWk  = (const float*)d_in[17];
  const float* fbk  = (const float*)d_in[18];
  const float* fWv  = (const float*)d_in[19];
  const float* fbv  = (const float*)d_in[20];
  const float* fWo  = (const float*)d_in[21];
  const float* fbo  = (const float*)d_in[22];
  const float* Wlin = (const float*)d_in[23];
  const float* blin = (const float*)d_in[24];
  const float* Wprj = (const float*)d_in[25];
  const float* bprj = (const float*)d_in[26];
  float* out = (float*)d_out;

  float* ws = (float*)d_ws;
  const size_t SZ = (size_t)64 * 512 * 512;   // 16,777,216
  float* b0 = ws;
  float* b1 = ws + SZ;
  float* b2 = ws + 2 * SZ;
  float* b3 = ws + 3 * SZ;
  float* kv   = ws + 4 * SZ;                  // 64*8*64*64 = 2,097,152
  float* z    = kv + 2097152;                 // 32768
  float* meanb = z + 32768;
  float* stdb  = meanb + 32768;
  float* lmu   = stdb + 32768;
  float* linv  = lmu + 32768;
  float* ybuf  = linv + 32768;                // 64*512*96 = 3,145,728

  dim3 gg(512, 8);

  // RevIN
  revin_stats_k<<<8192, 256, 0, stream>>>(x, meanb, stdb);
  revin_apply_k<<<dim3(16, 16, 64), dim3(32, 8), 0, stream>>>(x, meanb, stdb, rg, rb, b0);

  // --- temporal attention block (on (B,L,F), D=F) ---
  row_stats_ln_k<<<8192, 256, 0, stream>>>(b0, lmu, linv);
  gemm512k<1, 0, 1><<<gg, 256, 0, stream>>>(b0, tWq, tbq, nullptr, lmu, linv, n1g, n1b, b1);
  gemm512k<1, 0, 1><<<gg, 256, 0, stream>>>(b0, tWk, tbk, nullptr, lmu, linv, n1g, n1b, b2);
  gemm512k<0, 0, 1><<<gg, 256, 0, stream>>>(b0, tWv, tbv, nullptr, lmu, linv, n1g, n1b, b3);
  kv_reduce_k<<<512, 256, 0, stream>>>(b2, b3, kv, z);
  attn_out_k<<<dim3(32, 512), 256, 0, stream>>>(b1, kv, z);
  // Wo projection + residual, transposed write into (B,F,L) -> b3
  gemm512k<0, 2, 0><<<gg, 256, 0, stream>>>(b1, tWo, tbo, b0, nullptr, nullptr, nullptr, nullptr, b3);

  // --- feature attention block (on (B,F,L), D=L) ---
  row_stats_ln_k<<<8192, 256, 0, stream>>>(b3, lmu, linv);
  gemm512k<1, 0, 1><<<gg, 256, 0, stream>>>(b3, fWq, fbq, nullptr, lmu, linv, n2g, n2b, b0);
  gemm512k<1, 0, 1><<<gg, 256, 0, stream>>>(b3, fWk, fbk, nullptr, lmu, linv, n2g, n2b, b1);
  gemm512k<0, 0, 1><<<gg, 256, 0, stream>>>(b3, fWv, fbv, nullptr, lmu, linv, n2g, n2b, b2);
  kv_reduce_k<<<512, 256, 0, stream>>>(b1, b2, kv, z);
  attn_out_k<<<dim3(32, 512), 256, 0, stream>>>(b0, kv, z);
  // Wo projection + residual (same layout) -> b1 = h2 (B,F,L)
  gemm512k<0, 1, 0><<<gg, 256, 0, stream>>>(b0, fWo, fbo, b3, nullptr, nullptr, nullptr, nullptr, b1);

  // per-feature linear + denorm + projector
  feat_linear_k<<<512, 256, 0, stream>>>(b1, Wlin, blin, ybuf);
  final_out_k<<<64, 256, 0, stream>>>(ybuf, meanb, stdb, rg, rb, Wprj, bprj, out);
}

// Round 2
// 823.164 us; speedup vs baseline: 3.0104x; 3.0104x over previous
//
#include <hip/hip_runtime.h>
#include <hip/hip_bf16.h>
#include <cstdint>
#include <cstddef>

// LinearCrypto MI355X round 2: bf16 MFMA GEMMs (m97-style 128x128 tile,
// BK=64, global_load_lds + both-sides XOR swizzle), bf16 Q/K/V/attn-out.
// B=64, F=512, L=512, P=96, H=8, hd=64, M=B*512=32768

#define EPS_ATTN 1e-6f
#define EPS_LN   1e-5f
#define EPS_REVIN 1e-5f

typedef __attribute__((ext_vector_type(8))) short bf16x8;
typedef __attribute__((ext_vector_type(4))) float f32x4;
typedef __attribute__((ext_vector_type(8))) unsigned short u16x8;

__device__ __forceinline__ float bf2f(unsigned short u) {
  unsigned int x = ((unsigned int)u) << 16;
  return __builtin_bit_cast(float, x);
}
__device__ __forceinline__ unsigned short f2bf(float f) {
  __hip_bfloat16 h = __float2bfloat16(f);
  return __builtin_bit_cast(unsigned short, h);
}
__device__ __forceinline__ void gload16(const void* g, void* l) {
  __builtin_amdgcn_global_load_lds(
      (const __attribute__((address_space(1))) void*)g,
      (__attribute__((address_space(3))) void*)l, 16, 0, 0);
}

// ---------- RevIN stats ----------
__global__ __launch_bounds__(256) void revin_stats_k(const float* __restrict__ x,
                                                     float* __restrict__ meanb,
                                                     float* __restrict__ stdb) {
  int wid = threadIdx.x >> 6, lane = threadIdx.x & 63;
  int row = blockIdx.x * 4 + wid;
  const float* xr = x + (size_t)row * 512;
  float s1 = 0.f, s2 = 0.f;
#pragma unroll
  for (int i = 0; i < 8; ++i) {
    float v = xr[lane + i * 64];
    s1 += v; s2 += v * v;
  }
#pragma unroll
  for (int off = 32; off; off >>= 1) { s1 += __shfl_down(s1, off); s2 += __shfl_down(s2, off); }
  if (lane == 0) {
    float m = s1 * (1.f / 512.f);
    float var = fmaxf((s2 - 512.f * m * m) * (1.f / 511.f), 0.f);
    meanb[row] = m;
    stdb[row]  = sqrtf(var) + EPS_REVIN;
  }
}

// ---------- RevIN apply + transpose to (B,L,F) ----------
__global__ __launch_bounds__(256) void revin_apply_k(const float* __restrict__ x,
                                                     const float* __restrict__ meanb,
                                                     const float* __restrict__ stdb,
                                                     const float* __restrict__ rg,
                                                     const float* __restrict__ rb,
                                                     float* __restrict__ hA) {
  __shared__ float tile[32][33];
  int b = blockIdx.z;
  int f0 = blockIdx.y * 32, l0 = blockIdx.x * 32;
  int tx = threadIdx.x, ty = threadIdx.y;
  const float* xb = x + (size_t)b * 512 * 512;
#pragma unroll
  for (int k = 0; k < 32; k += 8) {
    int f = f0 + ty + k;
    float m = meanb[b * 512 + f], s = stdb[b * 512 + f];
    float v = xb[(size_t)f * 512 + l0 + tx];
    tile[ty + k][tx] = (v - m) / s * rg[f] + rb[f];
  }
  __syncthreads();
  float* hb = hA + (size_t)b * 512 * 512;
#pragma unroll
  for (int k = 0; k < 32; k += 8) {
    int l = l0 + ty + k;
    hb[(size_t)l * 512 + f0 + tx] = tile[tx][ty + k];
  }
}

// ---------- LayerNorm row stats ----------
__global__ __launch_bounds__(256) void row_stats_ln_k(const float* __restrict__ in,
                                                      float* __restrict__ mu,
                                                      float* __restrict__ inv) {
  int wid = threadIdx.x >> 6, lane = threadIdx.x & 63;
  int row = blockIdx.x * 4 + wid;
  const float* r = in + (size_t)row * 512;
  float s1 = 0.f, s2 = 0.f;
#pragma unroll
  for (int i = 0; i < 8; ++i) {
    float v = r[lane + i * 64];
    s1 += v; s2 += v * v;
  }
#pragma unroll
  for (int off = 32; off; off >>= 1) { s1 += __shfl_down(s1, off); s2 += __shfl_down(s2, off); }
  if (lane == 0) {
    float m = s1 * (1.f / 512.f);
    float var = fmaxf(s2 * (1.f / 512.f) - m * m, 0.f);
    mu[row]  = m;
    inv[row] = 1.f / sqrtf(var + EPS_LN);
  }
}

// ---------- LN apply + fp32->bf16 ----------
__global__ __launch_bounds__(256) void lnapply_bf16_k(const float* __restrict__ in,
                                                      const float* __restrict__ mu,
                                                      const float* __restrict__ inv,
                                                      const float* __restrict__ g,
                                                      const float* __restrict__ b,
                                                      unsigned short* __restrict__ o16) {
  int row = blockIdx.x * 4 + (threadIdx.x >> 6);
  int lane = threadIdx.x & 63;
  const float* r = in + (size_t)row * 512 + lane * 8;
  float m = mu[row], iv = inv[row];
  float4 v0 = *(const float4*)r;
  float4 v1 = *(const float4*)(r + 4);
  float4 g0 = *(const float4*)(g + lane * 8);
  float4 g1 = *(const float4*)(g + lane * 8 + 4);
  float4 b0 = *(const float4*)(b + lane * 8);
  float4 b1 = *(const float4*)(b + lane * 8 + 4);
  u16x8 o;
  o[0] = f2bf((v0.x - m) * iv * g0.x + b0.x);
  o[1] = f2bf((v0.y - m) * iv * g0.y + b0.y);
  o[2] = f2bf((v0.z - m) * iv * g0.z + b0.z);
  o[3] = f2bf((v0.w - m) * iv * g0.w + b0.w);
  o[4] = f2bf((v1.x - m) * iv * g1.x + b1.x);
  o[5] = f2bf((v1.y - m) * iv * g1.y + b1.y);
  o[6] = f2bf((v1.z - m) * iv * g1.z + b1.z);
  o[7] = f2bf((v1.w - m) * iv * g1.w + b1.w);
  *(u16x8*)(o16 + (size_t)row * 512 + lane * 8) = o;
}

// ---------- convert 8 (512x512) fp32 weights -> bf16 ----------
__global__ __launch_bounds__(256) void wconv_k(const float* w0, const float* w1,
                                               const float* w2, const float* w3,
                                               const float* w4, const float* w5,
                                               const float* w6, const float* w7,
                                               unsigned short* __restrict__ out) {
  const float* srcs[8] = {w0, w1, w2, w3, w4, w5, w6, w7};
  const float* s = srcs[blockIdx.y];
  size_t idx = (size_t)blockIdx.x * 2048 + threadIdx.x * 8;
  float4 v0 = *(const float4*)(s + idx);
  float4 v1 = *(const float4*)(s + idx + 4);
  u16x8 o;
  o[0] = f2bf(v0.x); o[1] = f2bf(v0.y); o[2] = f2bf(v0.z); o[3] = f2bf(v0.w);
  o[4] = f2bf(v1.x); o[5] = f2bf(v1.y); o[6] = f2bf(v1.z); o[7] = f2bf(v1.w);
  *(u16x8*)(out + (size_t)blockIdx.y * 262144 + idx) = o;
}

// ---------- bf16 MFMA GEMM: out[m,n] = A[m,:]·W[n,:] + bias ----------
// OMODE 0: bf16 out (ACT optional). OMODE 1: fp32 out + resid.
// OMODE 2: fp32 + resid, transposed write to (B,F,L) via swapped operands.
template <int ACT, int OMODE>
__global__ __launch_bounds__(256) void gemm_mfma_k(
    const unsigned short* __restrict__ A,    // [M][512] bf16
    const unsigned short* __restrict__ W,    // [512][512] bf16, [n][k]
    const float* __restrict__ bias,
    const float* __restrict__ resid,
    void* __restrict__ outp) {
  __shared__ unsigned short As[128 * 64] __attribute__((aligned(16)));
  __shared__ unsigned short Bs[128 * 64] __attribute__((aligned(16)));
  const int tid = threadIdx.x;
  const int w = tid >> 6, lane = tid & 63;
  const int m0 = blockIdx.x * 128, n0 = blockIdx.y * 128;
  const int wr = w >> 1, wc = w & 1;

  // staging: lane covers row r8 within 8-row sub-chunk, fetches swizzled slot
  const int r8 = lane >> 3;                 // 0..7
  const int s8 = lane & 7;                  // LDS slot written (linear)
  const int gslot = s8 ^ r8;                // global 16B-slot fetched (involution)
  const unsigned short* Ag = A + (size_t)(m0 + w * 32 + r8) * 512 + gslot * 8;
  const unsigned short* Wg = W + (size_t)(n0 + w * 32 + r8) * 512 + gslot * 8;
  unsigned short* Asw = &As[w * 2048];
  unsigned short* Bsw = &Bs[w * 2048];

  f32x4 acc[4][4] = {};
  for (int k0 = 0; k0 < 512; k0 += 64) {
#pragma unroll
    for (int c = 0; c < 4; ++c) {
      gload16(Ag + (size_t)c * 8 * 512 + k0, Asw + c * 512);
      gload16(Wg + (size_t)c * 8 * 512 + k0, Bsw + c * 512);
    }
    __syncthreads();
#pragma unroll
    for (int s = 0; s < 2; ++s) {
      bf16x8 fa[4], fb[4];
#pragma unroll
      for (int i = 0; i < 4; ++i) {
        int ra = wr * 64 + i * 16 + (lane & 15);
        int sa = (s * 4 + (lane >> 4)) ^ (ra & 7);
        fa[i] = *(const bf16x8*)&As[ra * 64 + sa * 8];
        int rb = wc * 64 + i * 16 + (lane & 15);
        int sb = (s * 4 + (lane >> 4)) ^ (rb & 7);
        fb[i] = *(const bf16x8*)&Bs[rb * 64 + sb * 8];
      }
#pragma unroll
      for (int i = 0; i < 4; ++i)
#pragma unroll
        for (int j = 0; j < 4; ++j) {
          if constexpr (OMODE == 2)
            acc[j][i] = __builtin_amdgcn_mfma_f32_16x16x32_bf16(fb[j], fa[i], acc[j][i], 0, 0, 0);
          else
            acc[i][j] = __builtin_amdgcn_mfma_f32_16x16x32_bf16(fa[i], fb[j], acc[i][j], 0, 0, 0);
        }
    }
    __syncthreads();
  }

  const int ro = (lane >> 4) * 4;     // D row offset within 16x16
  const int c16 = lane & 15;          // D col within 16x16

  if constexpr (OMODE == 2) {
    // acc[j][i]: D-row = f (W rows), D-col = m (=(b,l)); out (B,F,L) coalesced in l
    float* of = (float*)outp;
    const int b = m0 >> 9, l0 = m0 & 511;
#pragma unroll
    for (int j = 0; j < 4; ++j) {
#pragma unroll
      for (int i = 0; i < 4; ++i) {
        int f = n0 + wc * 64 + j * 16 + ro;
        int l = l0 + wr * 64 + i * 16 + c16;
#pragma unroll
        for (int r = 0; r < 4; ++r) {
          float val = acc[j][i][r] + bias[f + r] +
                      resid[((size_t)(b * 512) + l) * 512 + (f + r)];
          of[((size_t)(b * 512) + f + r) * 512 + l] = val;
        }
      }
    }
  } else {
#pragma unroll
    for (int i = 0; i < 4; ++i) {
#pragma unroll
      for (int j = 0; j < 4; ++j) {
        int gm = m0 + wr * 64 + i * 16 + ro;
        int gn = n0 + wc * 64 + j * 16 + c16;
        float bi = bias[gn];
#pragma unroll
        for (int r = 0; r < 4; ++r) {
          float val = acc[i][j][r] + bi;
          if constexpr (ACT == 1)
            val = (val > 0.f) ? val + 1.f : __expf(val);
          if constexpr (OMODE == 0) {
            ((unsigned short*)outp)[(size_t)(gm + r) * 512 + gn] = f2bf(val);
          } else {
            float* of = (float*)outp;
            of[(size_t)(gm + r) * 512 + gn] = val + resid[(size_t)(gm + r) * 512 + gn];
          }
        }
      }
    }
  }
}

// ---------- KV[b,h,d,e] = sum_n K[b,n,hd+d]*V[b,n,hd+e];  Z = sum_n K (bf16 in) ----------
__global__ __launch_bounds__(256) void kv_reduce_bf16_k(const unsigned short* __restrict__ K16,
                                                        const unsigned short* __restrict__ V16,
                                                        float* __restrict__ KV,
                                                        float* __restrict__ Z) {
  int bh = blockIdx.x;
  int b = bh >> 3, h = bh & 7;
  __shared__ float Ks[16][65];
  __shared__ float Vs[16][65];
  int tid = threadIdx.x;
  int tx = tid & 15, ty = tid >> 4;
  int lr = tid >> 4;
  int lc = (tid & 15) * 4;
  const unsigned short* Kp = K16 + (size_t)b * 262144 + h * 64 + lc;
  const unsigned short* Vp = V16 + (size_t)b * 262144 + h * 64 + lc;
  float acc[4][4] = {};
  float zac[4] = {};
  for (int n0 = 0; n0 < 512; n0 += 16) {
    ushort4 ku = *(const ushort4*)(Kp + (size_t)(n0 + lr) * 512);
    ushort4 vu = *(const ushort4*)(Vp + (size_t)(n0 + lr) * 512);
    Ks[lr][lc + 0] = bf2f(ku.x); Ks[lr][lc + 1] = bf2f(ku.y);
    Ks[lr][lc + 2] = bf2f(ku.z); Ks[lr][lc + 3] = bf2f(ku.w);
    Vs[lr][lc + 0] = bf2f(vu.x); Vs[lr][lc + 1] = bf2f(vu.y);
    Vs[lr][lc + 2] = bf2f(vu.z); Vs[lr][lc + 3] = bf2f(vu.w);
    __syncthreads();
#pragma unroll
    for (int n = 0; n < 16; ++n) {
      float kk[4], vv[4];
#pragma unroll
      for (int i = 0; i < 4; ++i) kk[i] = Ks[n][ty * 4 + i];
#pragma unroll
      for (int j = 0; j < 4; ++j) vv[j] = Vs[n][tx * 4 + j];
#pragma unroll
      for (int i = 0; i < 4; ++i) {
        zac[i] += kk[i];
#pragma unroll
        for (int j = 0; j < 4; ++j) acc[i][j] = fmaf(kk[i], vv[j], acc[i][j]);
      }
    }
    __syncthreads();
  }
  float* kvp = KV + (size_t)bh * 4096;
#pragma unroll
  for (int i = 0; i < 4; ++i)
#pragma unroll
    for (int j = 0; j < 4; ++j) kvp[(ty * 4 + i) * 64 + tx * 4 + j] = acc[i][j];
  if (tx == 0) {
#pragma unroll
    for (int i = 0; i < 4; ++i) Z[bh * 64 + ty * 4 + i] = zac[i];
  }
}

// ---------- O = (Q @ KV) / (Q·Z + eps), bf16 in/out ----------
__global__ __launch_bounds__(256) void attn_out_bf16_k(const unsigned short* __restrict__ Q16,
                                                       const float* __restrict__ KV,
                                                       const float* __restrict__ Z,
                                                       unsigned short* __restrict__ O16) {
  int bh = blockIdx.y;
  int b = bh >> 3, h = bh & 7;
  int n0 = blockIdx.x * 16;
  __shared__ float KVs[64][65];
  __shared__ float Qs[16][65];
  __shared__ float Zs[64];
  int tid = threadIdx.x;
  {
    int d = tid >> 2, c = (tid & 3) * 16;
    const float* kvp = KV + (size_t)bh * 4096 + d * 64 + c;
#pragma unroll
    for (int s = 0; s < 16; s += 4) {
      float4 v = *(const float4*)(kvp + s);
      KVs[d][c + s] = v.x; KVs[d][c + s + 1] = v.y; KVs[d][c + s + 2] = v.z; KVs[d][c + s + 3] = v.w;
    }
  }
  if (tid < 64) Zs[tid] = Z[bh * 64 + tid];
  const unsigned short* qb = Q16 + (size_t)(b * 512 + n0) * 512 + h * 64;
  {
    int n = tid >> 4, c = (tid & 15) * 4;
    ushort4 u = *(const ushort4*)(qb + (size_t)n * 512 + c);
    Qs[n][c] = bf2f(u.x); Qs[n][c + 1] = bf2f(u.y); Qs[n][c + 2] = bf2f(u.z); Qs[n][c + 3] = bf2f(u.w);
  }
  __syncthreads();
  int nl = tid >> 4, te = tid & 15;
  float a0 = 0.f, a1 = 0.f, a2 = 0.f, a3 = 0.f;
  float nrm = EPS_ATTN;
#pragma unroll
  for (int d = 0; d < 64; ++d) {
    float q = Qs[nl][d];
    nrm = fmaf(q, Zs[d], nrm);
    a0 = fmaf(q, KVs[d][te * 4 + 0], a0);
    a1 = fmaf(q, KVs[d][te * 4 + 1], a1);
    a2 = fmaf(q, KVs[d][te * 4 + 2], a2);
    a3 = fmaf(q, KVs[d][te * 4 + 3], a3);
  }
  float iv = 1.f / nrm;
  unsigned short* ob = O16 + (size_t)(b * 512 + n0) * 512 + h * 64;
  ushort4 o;
  o.x = f2bf(a0 * iv); o.y = f2bf(a1 * iv); o.z = f2bf(a2 * iv); o.w = f2bf(a3 * iv);
  *(ushort4*)(ob + (size_t)nl * 512 + te * 4) = o;
}

// ---------- y[b,f,p] = sum_l h2[b,f,l]*Wlin[f,p,l] + blin[f,p] ----------
__global__ __launch_bounds__(256) void feat_linear_k(const float* __restrict__ h2,
                                                     const float* __restrict__ Wlin,
                                                     const float* __restrict__ blin,
                                                     float* __restrict__ Y) {
  int f = blockIdx.x;
  __shared__ float Hs[64][65];
  __shared__ float Ws2[96][65];
  int tid = threadIdx.x;
  int tx = tid & 15, ty = tid >> 4;
  float acc[4][6] = {};
  for (int l0 = 0; l0 < 512; l0 += 64) {
    {
      int bb = tid >> 2, c = (tid & 3) * 16;
      const float* hp = h2 + ((size_t)bb * 512 + f) * 512 + l0 + c;
#pragma unroll
      for (int s = 0; s < 16; s += 4) {
        float4 v = *(const float4*)(hp + s);
        Hs[bb][c + s] = v.x; Hs[bb][c + s + 1] = v.y; Hs[bb][c + s + 2] = v.z; Hs[bb][c + s + 3] = v.w;
      }
    }
#pragma unroll
    for (int s = 0; s < 6; ++s) {
      int q = s * 256 + tid;
      int p = q >> 4, c = (q & 15) * 4;
      float4 v = *(const float4*)(Wlin + ((size_t)f * 96 + p) * 512 + l0 + c);
      Ws2[p][c] = v.x; Ws2[p][c + 1] = v.y; Ws2[p][c + 2] = v.z; Ws2[p][c + 3] = v.w;
    }
    __syncthreads();
#pragma unroll 8
    for (int l = 0; l < 64; ++l) {
      float hv[4], wv[6];
#pragma unroll
      for (int i = 0; i < 4; ++i) hv[i] = Hs[ty * 4 + i][l];
#pragma unroll
      for (int j = 0; j < 6; ++j) wv[j] = Ws2[tx * 6 + j][l];
#pragma unroll
      for (int i = 0; i < 4; ++i)
#pragma unroll
        for (int j = 0; j < 6; ++j) acc[i][j] = fmaf(hv[i], wv[j], acc[i][j]);
    }
    __syncthreads();
  }
#pragma unroll
  for (int i = 0; i < 4; ++i) {
    int b = ty * 4 + i;
#pragma unroll
    for (int j = 0; j < 6; ++j) {
      int p = tx * 6 + j;
      Y[((size_t)b * 512 + f) * 96 + p] = acc[i][j] + blin[f * 96 + p];
    }
  }
}

// ---------- final: denorm + projector ----------
__global__ __launch_bounds__(256) void final_out_k(const float* __restrict__ Y,
                                                   const float* __restrict__ meanb,
                                                   const float* __restrict__ stdb,
                                                   const float* __restrict__ rg,
                                                   const float* __restrict__ rb,
                                                   const float* __restrict__ Wproj,
                                                   const float* __restrict__ bproj,
                                                   float* __restrict__ out) {
  int b = blockIdx.x;
  __shared__ float cs[512];
  __shared__ float kred[4];
  int t = threadIdx.x;
  float kpart = 0.f;
  for (int f = t; f < 512; f += 256) {
    float sd = stdb[b * 512 + f], mn = meanb[b * 512 + f];
    float g = rg[f], rbv = rb[f], wp = Wproj[f];
    float c = wp * sd / g;
    cs[f] = c;
    kpart += wp * mn - c * rbv;
  }
#pragma unroll
  for (int off = 32; off; off >>= 1) kpart += __shfl_down(kpart, off);
  int wid = t >> 6, lane = t & 63;
  if (lane == 0) kred[wid] = kpart;
  __syncthreads();
  float K = kred[0] + kred[1] + kred[2] + kred[3] + bproj[0];
  if (t < 96) {
    float acc = 0.f;
    for (int f = 0; f < 512; ++f) acc = fmaf(cs[f], Y[((size_t)b * 512 + f) * 96 + t], acc);
    out[b * 96 + t] = acc + K;
  }
}

extern "C" void kernel_launch(void* const* d_in, const int* in_sizes, int n_in,
                              void* d_out, int out_size, void* d_ws, size_t ws_size,
                              hipStream_t stream) {
  const float* x    = (const float*)d_in[0];
  const float* rg   = (const float*)d_in[1];
  const float* rb   = (const float*)d_in[2];
  const float* n1g  = (const float*)d_in[3];
  const float* n1b  = (const float*)d_in[4];
  const float* n2g  = (const float*)d_in[5];
  const float* n2b  = (const float*)d_in[6];
  const float* tWq  = (const float*)d_in[7];
  const float* tbq  = (const float*)d_in[8];
  const float* tWk  = (const float*)d_in[9];
  const float* tbk  = (const float*)d_in[10];
  const float* tWv  = (const float*)d_in[11];
  const float* tbv  = (const float*)d_in[12];
  const float* tWo  = (const float*)d_in[13];
  const float* tbo  = (const float*)d_in[14];
  const float* fWq  = (const float*)d_in[15];
  const float* fbq  = (const float*)d_in[16];
  const float* fWk  = (const float*)d_in[17];
  const float* fbk  = (const float*)d_in[18];
  const float* fWv  = (const float*)d_in[19];
  const float* fbv  = (const float*)d_in[20];
  const float* fWo  = (const float*)d_in[21];
  const float* fbo  = (const float*)d_in[22];
  const float* Wlin = (const float*)d_in[23];
  const float* blin = (const float*)d_in[24];
  const float* Wprj = (const float*)d_in[25];
  const float* bprj = (const float*)d_in[26];
  float* out = (float*)d_out;

  const size_t SZ = (size_t)64 * 512 * 512;   // 16,777,216 elements
  char* p = (char*)d_ws;
  float* b0 = (float*)p;            p += SZ * 4;
  float* b3 = (float*)p;            p += SZ * 4;
  unsigned short* q16 = (unsigned short*)p; p += SZ * 2;
  unsigned short* k16 = (unsigned short*)p; p += SZ * 2;
  unsigned short* v16 = (unsigned short*)p; p += SZ * 2;
  unsigned short* abf = (unsigned short*)p; p += SZ * 2;
  unsigned short* wbf = (unsigned short*)p; p += (size_t)8 * 262144 * 2;
  float* kv   = (float*)p;          p += (size_t)2097152 * 4;
  float* z    = (float*)p;          p += 32768 * 4;
  float* meanb = (float*)p;         p += 32768 * 4;
  float* stdb  = (float*)p;         p += 32768 * 4;
  float* lmu   = (float*)p;         p += 32768 * 4;
  float* linv  = (float*)p;         p += 32768 * 4;
  float* ybuf  = (float*)q16;       // alias: q16 dead before feat_linear

  dim3 gg(256, 4);

  wconv_k<<<dim3(128, 8), 256, 0, stream>>>(tWq, tWk, tWv, tWo, fWq, fWk, fWv, fWo, wbf);
  revin_stats_k<<<8192, 256, 0, stream>>>(x, meanb, stdb);
  revin_apply_k<<<dim3(16, 16, 64), dim3(32, 8), 0, stream>>>(x, meanb, stdb, rg, rb, b0);

  // --- temporal attention block (on (B,L,F)) ---
  row_stats_ln_k<<<8192, 256, 0, stream>>>(b0, lmu, linv);
  lnapply_bf16_k<<<8192, 256, 0, stream>>>(b0, lmu, linv, n1g, n1b, abf);
  gemm_mfma_k<1, 0><<<gg, 256, 0, stream>>>(abf, wbf + 0 * 262144, tbq, nullptr, q16);
  gemm_mfma_k<1, 0><<<gg, 256, 0, stream>>>(abf, wbf + 1 * 262144, tbk, nullptr, k16);
  gemm_mfma_k<0, 0><<<gg, 256, 0, stream>>>(abf, wbf + 2 * 262144, tbv, nullptr, v16);
  kv_reduce_bf16_k<<<512, 256, 0, stream>>>(k16, v16, kv, z);
  attn_out_bf16_k<<<dim3(32, 512), 256, 0, stream>>>(q16, kv, z, v16);
  gemm_mfma_k<0, 2><<<gg, 256, 0, stream>>>(v16, wbf + 3 * 262144, tbo, b0, b3);

  // --- feature attention block (on (B,F,L)) ---
  row_stats_ln_k<<<8192, 256, 0, stream>>>(b3, lmu, linv);
  lnapply_bf16_k<<<8192, 256, 0, stream>>>(b3, lmu, linv, n2g, n2b, abf);
  gemm_mfma_k<1, 0><<<gg, 256, 0, stream>>>(abf, wbf + 4 * 262144, fbq, nullptr, q16);
  gemm_mfma_k<1, 0><<<gg, 256, 0, stream>>>(abf, wbf + 5 * 262144, fbk, nullptr, k16);
  gemm_mfma_k<0, 0><<<gg, 256, 0, stream>>>(abf, wbf + 6 * 262144, fbv, nullptr, v16);
  kv_reduce_bf16_k<<<512, 256, 0, stream>>>(k16, v16, kv, z);
  attn_out_bf16_k<<<dim3(32, 512), 256, 0, stream>>>(q16, kv, z, v16);
  gemm_mfma_k<0, 1><<<gg, 256, 0, stream>>>(v16, wbf + 7 * 262144, fbo, b3, b0);

  // tail: per-feature linear + denorm + projector
  feat_linear_k<<<512, 256, 0, stream>>>(b0, Wlin, blin, ybuf);
  final_out_k<<<64, 256, 0, stream>>>(ybuf, meanb, stdb, rg, rb, Wprj, bprj, out);
}

// Round 3
// 553.371 us; speedup vs baseline: 4.4781x; 1.4875x over previous
//
#include <hip/hip_runtime.h>
#include <hip/hip_bf16.h>
#include <cstdint>
#include <cstddef>

// LinearCrypto MI355X round 3: MFMA attention path (transposed K/V layouts),
// fused LN, coalesced Wo1 residual-from-x.
// B=64, F=512, L=512, P=96, H=8, hd=64, M=B*512=32768

#define EPS_ATTN 1e-6f
#define EPS_LN   1e-5f
#define EPS_REVIN 1e-5f

typedef __attribute__((ext_vector_type(8))) short bf16x8;
typedef __attribute__((ext_vector_type(4))) float f32x4;
typedef __attribute__((ext_vector_type(8))) unsigned short u16x8;

__device__ __forceinline__ float bf2f(unsigned short u) {
  unsigned int x = ((unsigned int)u) << 16;
  return __builtin_bit_cast(float, x);
}
__device__ __forceinline__ unsigned short f2bf(float f) {
  __hip_bfloat16 h = __float2bfloat16(f);
  return __builtin_bit_cast(unsigned short, h);
}
__device__ __forceinline__ void gload16(const void* g, void* l) {
  __builtin_amdgcn_global_load_lds(
      (const __attribute__((address_space(1))) void*)g,
      (__attribute__((address_space(3))) void*)l, 16, 0, 0);
}

// ---------- RevIN stats ----------
__global__ __launch_bounds__(256) void revin_stats_k(const float* __restrict__ x,
                                                     float* __restrict__ meanb,
                                                     float* __restrict__ stdb) {
  int wid = threadIdx.x >> 6, lane = threadIdx.x & 63;
  int row = blockIdx.x * 4 + wid;
  const float* xr = x + (size_t)row * 512;
  float s1 = 0.f, s2 = 0.f;
#pragma unroll
  for (int i = 0; i < 8; ++i) {
    float v = xr[lane + i * 64];
    s1 += v; s2 += v * v;
  }
#pragma unroll
  for (int off = 32; off; off >>= 1) { s1 += __shfl_down(s1, off); s2 += __shfl_down(s2, off); }
  if (lane == 0) {
    float m = s1 * (1.f / 512.f);
    float var = fmaxf((s2 - 512.f * m * m) * (1.f / 511.f), 0.f);
    meanb[row] = m;
    stdb[row]  = sqrtf(var) + EPS_REVIN;
  }
}

// ---------- RevIN apply + transpose to (B,L,F) ----------
__global__ __launch_bounds__(256) void revin_apply_k(const float* __restrict__ x,
                                                     const float* __restrict__ meanb,
                                                     const float* __restrict__ stdb,
                                                     const float* __restrict__ rg,
                                                     const float* __restrict__ rb,
                                                     float* __restrict__ hA) {
  __shared__ float tile[32][33];
  int b = blockIdx.z;
  int f0 = blockIdx.y * 32, l0 = blockIdx.x * 32;
  int tx = threadIdx.x, ty = threadIdx.y;
  const float* xb = x + (size_t)b * 512 * 512;
#pragma unroll
  for (int k = 0; k < 32; k += 8) {
    int f = f0 + ty + k;
    float m = meanb[b * 512 + f], s = stdb[b * 512 + f];
    float v = xb[(size_t)f * 512 + l0 + tx];
    tile[ty + k][tx] = (v - m) / s * rg[f] + rb[f];
  }
  __syncthreads();
  float* hb = hA + (size_t)b * 512 * 512;
#pragma unroll
  for (int k = 0; k < 32; k += 8) {
    int l = l0 + ty + k;
    hb[(size_t)l * 512 + f0 + tx] = tile[tx][ty + k];
  }
}

// ---------- fused LayerNorm (stats + apply) fp32 -> bf16 ----------
__global__ __launch_bounds__(256) void ln_fused_k(const float* __restrict__ in,
                                                  const float* __restrict__ g,
                                                  const float* __restrict__ bq,
                                                  unsigned short* __restrict__ o16) {
  int row = blockIdx.x * 4 + (threadIdx.x >> 6);
  int lane = threadIdx.x & 63;
  const float* r = in + (size_t)row * 512 + lane * 8;
  float4 v0 = *(const float4*)r;
  float4 v1 = *(const float4*)(r + 4);
  float s1 = v0.x + v0.y + v0.z + v0.w + v1.x + v1.y + v1.z + v1.w;
  float s2 = v0.x * v0.x + v0.y * v0.y + v0.z * v0.z + v0.w * v0.w +
             v1.x * v1.x + v1.y * v1.y + v1.z * v1.z + v1.w * v1.w;
#pragma unroll
  for (int off = 1; off < 64; off <<= 1) {
    s1 += __shfl_xor(s1, off);
    s2 += __shfl_xor(s2, off);
  }
  float m = s1 * (1.f / 512.f);
  float var = fmaxf(s2 * (1.f / 512.f) - m * m, 0.f);
  float iv = 1.f / sqrtf(var + EPS_LN);
  float4 g0 = *(const float4*)(g + lane * 8);
  float4 g1 = *(const float4*)(g + lane * 8 + 4);
  float4 b0 = *(const float4*)(bq + lane * 8);
  float4 b1 = *(const float4*)(bq + lane * 8 + 4);
  u16x8 o;
  o[0] = f2bf((v0.x - m) * iv * g0.x + b0.x);
  o[1] = f2bf((v0.y - m) * iv * g0.y + b0.y);
  o[2] = f2bf((v0.z - m) * iv * g0.z + b0.z);
  o[3] = f2bf((v0.w - m) * iv * g0.w + b0.w);
  o[4] = f2bf((v1.x - m) * iv * g1.x + b1.x);
  o[5] = f2bf((v1.y - m) * iv * g1.y + b1.y);
  o[6] = f2bf((v1.z - m) * iv * g1.z + b1.z);
  o[7] = f2bf((v1.w - m) * iv * g1.w + b1.w);
  *(u16x8*)(o16 + (size_t)row * 512 + lane * 8) = o;
}

// ---------- convert 8 (512x512) fp32 weights -> bf16 ----------
__global__ __launch_bounds__(256) void wconv_k(const float* w0, const float* w1,
                                               const float* w2, const float* w3,
                                               const float* w4, const float* w5,
                                               const float* w6, const float* w7,
                                               unsigned short* __restrict__ out) {
  const float* srcs[8] = {w0, w1, w2, w3, w4, w5, w6, w7};
  const float* s = srcs[blockIdx.y];
  size_t idx = (size_t)blockIdx.x * 2048 + threadIdx.x * 8;
  float4 v0 = *(const float4*)(s + idx);
  float4 v1 = *(const float4*)(s + idx + 4);
  u16x8 o;
  o[0] = f2bf(v0.x); o[1] = f2bf(v0.y); o[2] = f2bf(v0.z); o[3] = f2bf(v0.w);
  o[4] = f2bf(v1.x); o[5] = f2bf(v1.y); o[6] = f2bf(v1.z); o[7] = f2bf(v1.w);
  *(u16x8*)(out + (size_t)blockIdx.y * 262144 + idx) = o;
}

// ---------- bf16 MFMA GEMM ----------
// OMODE 0: bf16 out natural [m][n] (ACT optional)
// OMODE 1: fp32 out + resid natural (in-place safe)
// OMODE 2: fp32 transposed write to (B,F,L) + residual recomputed from x
// OMODE 3: bf16 transposed write to (B,F,L) (ACT optional)  [K^T/V^T layouts]
template <int ACT, int OMODE>
__global__ __launch_bounds__(256) void gemm_mfma_k(
    const unsigned short* __restrict__ A,    // [M][512] bf16
    const unsigned short* __restrict__ W,    // [512][512] bf16, [n][k]
    const float* __restrict__ bias,
    const float* __restrict__ resid,
    const float* __restrict__ xr,
    const float* __restrict__ mbp,
    const float* __restrict__ sbp,
    const float* __restrict__ rgp,
    const float* __restrict__ rbp,
    void* __restrict__ outp) {
  __shared__ unsigned short As[128 * 64] __attribute__((aligned(16)));
  __shared__ unsigned short Bs[128 * 64] __attribute__((aligned(16)));
  const int tid = threadIdx.x;
  const int w = tid >> 6, lane = tid & 63;
  const int m0 = blockIdx.x * 128, n0 = blockIdx.y * 128;
  const int wr = w >> 1, wc = w & 1;

  const int r8 = lane >> 3;
  const int s8 = lane & 7;
  const int gslot = s8 ^ r8;
  const unsigned short* Ag = A + (size_t)(m0 + w * 32 + r8) * 512 + gslot * 8;
  const unsigned short* Wg = W + (size_t)(n0 + w * 32 + r8) * 512 + gslot * 8;
  unsigned short* Asw = &As[w * 2048];
  unsigned short* Bsw = &Bs[w * 2048];

  f32x4 acc[4][4] = {};
  for (int k0 = 0; k0 < 512; k0 += 64) {
#pragma unroll
    for (int c = 0; c < 4; ++c) {
      gload16(Ag + (size_t)c * 8 * 512 + k0, Asw + c * 512);
      gload16(Wg + (size_t)c * 8 * 512 + k0, Bsw + c * 512);
    }
    __syncthreads();
#pragma unroll
    for (int s = 0; s < 2; ++s) {
      bf16x8 fa[4], fb[4];
#pragma unroll
      for (int i = 0; i < 4; ++i) {
        int ra = wr * 64 + i * 16 + (lane & 15);
        int sa = (s * 4 + (lane >> 4)) ^ (ra & 7);
        fa[i] = *(const bf16x8*)&As[ra * 64 + sa * 8];
        int rb = wc * 64 + i * 16 + (lane & 15);
        int sb = (s * 4 + (lane >> 4)) ^ (rb & 7);
        fb[i] = *(const bf16x8*)&Bs[rb * 64 + sb * 8];
      }
#pragma unroll
      for (int i = 0; i < 4; ++i)
#pragma unroll
        for (int j = 0; j < 4; ++j) {
          if constexpr (OMODE >= 2)
            acc[j][i] = __builtin_amdgcn_mfma_f32_16x16x32_bf16(fb[j], fa[i], acc[j][i], 0, 0, 0);
          else
            acc[i][j] = __builtin_amdgcn_mfma_f32_16x16x32_bf16(fa[i], fb[j], acc[i][j], 0, 0, 0);
        }
    }
    __syncthreads();
  }

  const int ro = (lane >> 4) * 4;
  const int c16 = lane & 15;

  if constexpr (OMODE >= 2) {
    float* of = (float*)outp;
    unsigned short* ob = (unsigned short*)outp;
    const int b = m0 >> 9, l0 = m0 & 511;
#pragma unroll
    for (int j = 0; j < 4; ++j) {
#pragma unroll
      for (int i = 0; i < 4; ++i) {
        int f = n0 + wc * 64 + j * 16 + ro;
        int l = l0 + wr * 64 + i * 16 + c16;
#pragma unroll
        for (int r = 0; r < 4; ++r) {
          float val = acc[j][i][r] + bias[f + r];
          size_t oidx = ((size_t)(b * 512) + f + r) * 512 + l;
          if constexpr (OMODE == 3) {
            if constexpr (ACT == 1)
              val = (val > 0.f) ? val + 1.f : __expf(val);
            ob[oidx] = f2bf(val);
          } else {
            float coef = rgp[f + r] / sbp[b * 512 + f + r];
            float off2 = rbp[f + r] - mbp[b * 512 + f + r] * coef;
            of[oidx] = val + xr[oidx] * coef + off2;
          }
        }
      }
    }
  } else {
#pragma unroll
    for (int i = 0; i < 4; ++i) {
#pragma unroll
      for (int j = 0; j < 4; ++j) {
        int gm = m0 + wr * 64 + i * 16 + ro;
        int gn = n0 + wc * 64 + j * 16 + c16;
        float bi = bias[gn];
#pragma unroll
        for (int r = 0; r < 4; ++r) {
          float val = acc[i][j][r] + bi;
          if constexpr (ACT == 1)
            val = (val > 0.f) ? val + 1.f : __expf(val);
          if constexpr (OMODE == 0) {
            ((unsigned short*)outp)[(size_t)(gm + r) * 512 + gn] = f2bf(val);
          } else {
            float* of = (float*)outp;
            of[(size_t)(gm + r) * 512 + gn] = val + resid[(size_t)(gm + r) * 512 + gn];
          }
        }
      }
    }
  }
}

// ---------- KVT[e][d] = sum_n VT[e][n]*KT[d][n]; Z[d] = sum_n KT[d][n] (MFMA) ----------
__global__ __launch_bounds__(256) void kv_mfma_k(const unsigned short* __restrict__ KT,
                                                 const unsigned short* __restrict__ VT,
                                                 unsigned short* __restrict__ KVTo,
                                                 float* __restrict__ Zo) {
  int bh = blockIdx.x;
  int tid = threadIdx.x, w = tid >> 6, lane = tid & 63;
  int r16 = lane & 15, g = lane >> 4;
  const unsigned short* vb = VT + ((size_t)bh * 64 + w * 16 + r16) * 512 + g * 8;
  const unsigned short* kb = KT + ((size_t)bh * 64 + r16) * 512 + g * 8;
  f32x4 acc[4] = {};
  float zp[4] = {};
  for (int n0 = 0; n0 < 512; n0 += 32) {
    bf16x8 vf = *(const bf16x8*)(vb + n0);
#pragma unroll
    for (int j = 0; j < 4; ++j) {
      bf16x8 kf = *(const bf16x8*)(kb + (size_t)j * 16 * 512 + n0);
#pragma unroll
      for (int q = 0; q < 8; ++q) zp[j] += bf2f((unsigned short)kf[q]);
      acc[j] = __builtin_amdgcn_mfma_f32_16x16x32_bf16(vf, kf, acc[j], 0, 0, 0);
    }
  }
  int e = w * 16 + g * 4;
  unsigned short* kvo = KVTo + (size_t)bh * 4096;
#pragma unroll
  for (int j = 0; j < 4; ++j)
#pragma unroll
    for (int r = 0; r < 4; ++r)
      kvo[(size_t)(e + r) * 64 + j * 16 + r16] = f2bf(acc[j][r]);
#pragma unroll
  for (int j = 0; j < 4; ++j) {
    zp[j] += __shfl_xor(zp[j], 16);
    zp[j] += __shfl_xor(zp[j], 32);
  }
  if (w == 0 && lane < 16) {
#pragma unroll
    for (int j = 0; j < 4; ++j) Zo[(size_t)bh * 64 + j * 16 + lane] = zp[j];
  }
}

// ---------- O[m][h*64+e] = (Q@KVT^T)/(Q·Z+eps), in-place over Q (MFMA) ----------
__global__ __launch_bounds__(512) void attn_mfma_k(unsigned short* __restrict__ Q16,
                                                   const unsigned short* __restrict__ KVT,
                                                   const float* __restrict__ Z) {
  __shared__ unsigned short kvs[32768] __attribute__((aligned(16)));  // 64KB swizzled
  __shared__ float Zs[512];
  int tid = threadIdx.x;
  int b = blockIdx.x >> 2;
  int m0 = blockIdx.x * 128;
  const unsigned short* kg = KVT + (size_t)b * 32768;
#pragma unroll
  for (int t = 0; t < 8; ++t) {
    int c = tid + t * 512;
    int e = (c >> 3) & 63;
    u16x8 v = *(const u16x8*)(kg + (size_t)c * 8);
    *(u16x8*)((char*)kvs + ((c * 16) ^ ((e & 7) << 4))) = v;
  }
  Zs[tid] = Z[(size_t)b * 512 + tid];
  __syncthreads();

  int w = tid >> 6, lane = tid & 63;
  int r16 = lane & 15, g = lane >> 4;
  unsigned short* qrow = Q16 + (size_t)(m0 + w * 16 + r16) * 512;
  int orow0 = m0 + w * 16 + g * 4;

  for (int h = 0; h < 8; ++h) {
    bf16x8 q0 = *(const bf16x8*)(qrow + h * 64 + g * 8);
    bf16x8 q1 = *(const bf16x8*)(qrow + h * 64 + 32 + g * 8);
    const float* zh = Zs + h * 64;
    float4 z0 = *(const float4*)(zh + g * 8);
    float4 z0b = *(const float4*)(zh + g * 8 + 4);
    float4 z1 = *(const float4*)(zh + 32 + g * 8);
    float4 z1b = *(const float4*)(zh + 32 + g * 8 + 4);
    float np = 0.f;
    np = fmaf(bf2f((unsigned short)q0[0]), z0.x, np);
    np = fmaf(bf2f((unsigned short)q0[1]), z0.y, np);
    np = fmaf(bf2f((unsigned short)q0[2]), z0.z, np);
    np = fmaf(bf2f((unsigned short)q0[3]), z0.w, np);
    np = fmaf(bf2f((unsigned short)q0[4]), z0b.x, np);
    np = fmaf(bf2f((unsigned short)q0[5]), z0b.y, np);
    np = fmaf(bf2f((unsigned short)q0[6]), z0b.z, np);
    np = fmaf(bf2f((unsigned short)q0[7]), z0b.w, np);
    np = fmaf(bf2f((unsigned short)q1[0]), z1.x, np);
    np = fmaf(bf2f((unsigned short)q1[1]), z1.y, np);
    np = fmaf(bf2f((unsigned short)q1[2]), z1.z, np);
    np = fmaf(bf2f((unsigned short)q1[3]), z1.w, np);
    np = fmaf(bf2f((unsigned short)q1[4]), z1b.x, np);
    np = fmaf(bf2f((unsigned short)q1[5]), z1b.y, np);
    np = fmaf(bf2f((unsigned short)q1[6]), z1b.z, np);
    np = fmaf(bf2f((unsigned short)q1[7]), z1b.w, np);

    f32x4 acc[4] = {};
#pragma unroll
    for (int j = 0; j < 4; ++j) {
      int e = j * 16 + r16;
      int byte0 = h * 8192 + e * 128;
      int sw = (e & 7) << 4;
      bf16x8 k0 = *(const bf16x8*)((char*)kvs + ((byte0 + g * 16) ^ sw));
      bf16x8 k1 = *(const bf16x8*)((char*)kvs + ((byte0 + 64 + g * 16) ^ sw));
      acc[j] = __builtin_amdgcn_mfma_f32_16x16x32_bf16(q0, k0, acc[j], 0, 0, 0);
      acc[j] = __builtin_amdgcn_mfma_f32_16x16x32_bf16(q1, k1, acc[j], 0, 0, 0);
    }
    np += __shfl_xor(np, 16);
    np += __shfl_xor(np, 32);
    float inv = 1.f / (np + EPS_ATTN);
    float inv4[4];
#pragma unroll
    for (int r = 0; r < 4; ++r) inv4[r] = __shfl(inv, g * 4 + r);
#pragma unroll
    for (int j = 0; j < 4; ++j)
#pragma unroll
      for (int r = 0; r < 4; ++r)
        Q16[(size_t)(orow0 + r) * 512 + h * 64 + j * 16 + r16] = f2bf(acc[j][r] * inv4[r]);
  }
}

// ---------- y[b,f,p] = sum_l h2[b,f,l]*Wlin[f,p,l] + blin[f,p] ----------
__global__ __launch_bounds__(256) void feat_linear_k(const float* __restrict__ h2,
                                                     const float* __restrict__ Wlin,
                                                     const float* __restrict__ blin,
                                                     float* __restrict__ Y) {
  int f = blockIdx.x;
  __shared__ float Hs[64][65];
  __shared__ float Ws2[96][65];
  int tid = threadIdx.x;
  int tx = tid & 15, ty = tid >> 4;
  float acc[4][6] = {};
  for (int l0 = 0; l0 < 512; l0 += 64) {
    {
      int bb = tid >> 2, c = (tid & 3) * 16;
      const float* hp = h2 + ((size_t)bb * 512 + f) * 512 + l0 + c;
#pragma unroll
      for (int s = 0; s < 16; s += 4) {
        float4 v = *(const float4*)(hp + s);
        Hs[bb][c + s] = v.x; Hs[bb][c + s + 1] = v.y; Hs[bb][c + s + 2] = v.z; Hs[bb][c + s + 3] = v.w;
      }
    }
#pragma unroll
    for (int s = 0; s < 6; ++s) {
      int q = s * 256 + tid;
      int p = q >> 4, c = (q & 15) * 4;
      float4 v = *(const float4*)(Wlin + ((size_t)f * 96 + p) * 512 + l0 + c);
      Ws2[p][c] = v.x; Ws2[p][c + 1] = v.y; Ws2[p][c + 2] = v.z; Ws2[p][c + 3] = v.w;
    }
    __syncthreads();
#pragma unroll 8
    for (int l = 0; l < 64; ++l) {
      float hv[4], wv[6];
#pragma unroll
      for (int i = 0; i < 4; ++i) hv[i] = Hs[ty * 4 + i][l];
#pragma unroll
      for (int j = 0; j < 6; ++j) wv[j] = Ws2[tx * 6 + j][l];
#pragma unroll
      for (int i = 0; i < 4; ++i)
#pragma unroll
        for (int j = 0; j < 6; ++j) acc[i][j] = fmaf(hv[i], wv[j], acc[i][j]);
    }
    __syncthreads();
  }
#pragma unroll
  for (int i = 0; i < 4; ++i) {
    int b = ty * 4 + i;
#pragma unroll
    for (int j = 0; j < 6; ++j) {
      int p = tx * 6 + j;
      Y[((size_t)b * 512 + f) * 96 + p] = acc[i][j] + blin[f * 96 + p];
    }
  }
}

// ---------- final: denorm + projector ----------
__global__ __launch_bounds__(256) void final_out_k(const float* __restrict__ Y,
                                                   const float* __restrict__ meanb,
                                                   const float* __restrict__ stdb,
                                                   const float* __restrict__ rg,
                                                   const float* __restrict__ rb,
                                                   const float* __restrict__ Wproj,
                                                   const float* __restrict__ bproj,
                                                   float* __restrict__ out) {
  int b = blockIdx.x;
  __shared__ float cs[512];
  __shared__ float kred[4];
  int t = threadIdx.x;
  float kpart = 0.f;
  for (int f = t; f < 512; f += 256) {
    float sd = stdb[b * 512 + f], mn = meanb[b * 512 + f];
    float g = rg[f], rbv = rb[f], wp = Wproj[f];
    float c = wp * sd / g;
    cs[f] = c;
    kpart += wp * mn - c * rbv;
  }
#pragma unroll
  for (int off = 32; off; off >>= 1) kpart += __shfl_down(kpart, off);
  int wid = t >> 6, lane = t & 63;
  if (lane == 0) kred[wid] = kpart;
  __syncthreads();
  float K = kred[0] + kred[1] + kred[2] + kred[3] + bproj[0];
  if (t < 96) {
    float acc = 0.f;
    for (int f = 0; f < 512; ++f) acc = fmaf(cs[f], Y[((size_t)b * 512 + f) * 96 + t], acc);
    out[b * 96 + t] = acc + K;
  }
}

extern "C" void kernel_launch(void* const* d_in, const int* in_sizes, int n_in,
                              void* d_out, int out_size, void* d_ws, size_t ws_size,
                              hipStream_t stream) {
  const float* x    = (const float*)d_in[0];
  const float* rg   = (const float*)d_in[1];
  const float* rb   = (const float*)d_in[2];
  const float* n1g  = (const float*)d_in[3];
  const float* n1b  = (const float*)d_in[4];
  const float* n2g  = (const float*)d_in[5];
  const float* n2b  = (const float*)d_in[6];
  const float* tWq  = (const float*)d_in[7];
  const float* tbq  = (const float*)d_in[8];
  const float* tWk  = (const float*)d_in[9];
  const float* tbk  = (const float*)d_in[10];
  const float* tWv  = (const float*)d_in[11];
  const float* tbv  = (const float*)d_in[12];
  const float* tWo  = (const float*)d_in[13];
  const float* tbo  = (const float*)d_in[14];
  const float* fWq  = (const float*)d_in[15];
  const float* fbq  = (const float*)d_in[16];
  const float* fWk  = (const float*)d_in[17];
  const float* fbk  = (const float*)d_in[18];
  const float* fWv  = (const float*)d_in[19];
  const float* fbv  = (const float*)d_in[20];
  const float* fWo  = (const float*)d_in[21];
  const float* fbo  = (const float*)d_in[22];
  const float* Wlin = (const float*)d_in[23];
  const float* blin = (const float*)d_in[24];
  const float* Wprj = (const float*)d_in[25];
  const float* bprj = (const float*)d_in[26];
  float* out = (float*)d_out;

  const size_t SZ = (size_t)64 * 512 * 512;
  char* p = (char*)d_ws;
  float* b0 = (float*)p;            p += SZ * 4;    // 64MB, (B,L,F) then (B,F,L)
  unsigned short* q16 = (unsigned short*)p; p += SZ * 2;
  unsigned short* k16 = (unsigned short*)p; p += SZ * 2;   // KT layout
  unsigned short* v16 = (unsigned short*)p; p += SZ * 2;   // VT layout
  unsigned short* abf = (unsigned short*)p; p += SZ * 2;   // LN output / ybuf alias
  unsigned short* wbf = (unsigned short*)p; p += (size_t)8 * 262144 * 2;
  unsigned short* kvt = (unsigned short*)p; p += (size_t)512 * 4096 * 2;  // 4MB
  float* z     = (float*)p;         p += (size_t)512 * 64 * 4;
  float* meanb = (float*)p;         p += 32768 * 4;
  float* stdb  = (float*)p;         p += 32768 * 4;
  float* ybuf  = (float*)abf;       // abf dead before feat_linear

  dim3 gg(256, 4);
  const float* np = nullptr;

  wconv_k<<<dim3(128, 8), 256, 0, stream>>>(tWq, tWk, tWv, tWo, fWq, fWk, fWv, fWo, wbf);
  revin_stats_k<<<8192, 256, 0, stream>>>(x, meanb, stdb);
  revin_apply_k<<<dim3(16, 16, 64), dim3(32, 8), 0, stream>>>(x, meanb, stdb, rg, rb, b0);

  // --- temporal attention block (on (B,L,F)) ---
  ln_fused_k<<<8192, 256, 0, stream>>>(b0, n1g, n1b, abf);
  gemm_mfma_k<1, 0><<<gg, 256, 0, stream>>>(abf, wbf + 0 * 262144, tbq, np, np, np, np, np, np, q16);
  gemm_mfma_k<1, 3><<<gg, 256, 0, stream>>>(abf, wbf + 1 * 262144, tbk, np, np, np, np, np, np, k16);
  gemm_mfma_k<0, 3><<<gg, 256, 0, stream>>>(abf, wbf + 2 * 262144, tbv, np, np, np, np, np, np, v16);
  kv_mfma_k<<<512, 256, 0, stream>>>(k16, v16, kvt, z);
  attn_mfma_k<<<256, 512, 0, stream>>>(q16, kvt, z);
  // Wo1: transposed write + residual recomputed from x  -> b0 becomes (B,F,L)
  gemm_mfma_k<0, 2><<<gg, 256, 0, stream>>>(q16, wbf + 3 * 262144, tbo, np, x, meanb, stdb, rg, rb, b0);

  // --- feature attention block (on (B,F,L)) ---
  ln_fused_k<<<8192, 256, 0, stream>>>(b0, n2g, n2b, abf);
  gemm_mfma_k<1, 0><<<gg, 256, 0, stream>>>(abf, wbf + 4 * 262144, fbq, np, np, np, np, np, np, q16);
  gemm_mfma_k<1, 3><<<gg, 256, 0, stream>>>(abf, wbf + 5 * 262144, fbk, np, np, np, np, np, np, k16);
  gemm_mfma_k<0, 3><<<gg, 256, 0, stream>>>(abf, wbf + 6 * 262144, fbv, np, np, np, np, np, np, v16);
  kv_mfma_k<<<512, 256, 0, stream>>>(k16, v16, kvt, z);
  attn_mfma_k<<<256, 512, 0, stream>>>(q16, kvt, z);
  // Wo2: natural write + residual, in-place over b0
  gemm_mfma_k<0, 1><<<gg, 256, 0, stream>>>(q16, wbf + 7 * 262144, fbo, b0, np, np, np, np, np, b0);

  // tail
  feat_linear_k<<<512, 256, 0, stream>>>(b0, Wlin, blin, ybuf);
  final_out_k<<<64, 256, 0, stream>>>(ybuf, meanb, stdb, rg, rb, Wprj, bprj, out);
}